// Round 1
// baseline (358.389 us; speedup 1.0000x reference)
//
#include <hip/hip_runtime.h>
#include <hip/hip_bf16.h>

#define HID 1024
#define NH 8
#define HD 128
#define BB 2
#define SS 2048
#define CHK 128
#define NCH 16   // SS/CHK

typedef __attribute__((ext_vector_type(8))) short short8;
typedef __attribute__((ext_vector_type(4))) float f32x4;

static __device__ __forceinline__ float b2f(unsigned short u){
  unsigned int x = ((unsigned int)u) << 16; float f;
  __builtin_memcpy(&f, &x, 4); return f;
}
static __device__ __forceinline__ unsigned short f2b(float f){
  unsigned int x; __builtin_memcpy(&x, &f, 4);
  x += 0x7fffu + ((x >> 16) & 1u);
  return (unsigned short)(x >> 16);
}
static __device__ __forceinline__ float head_gamma(int h){
  // gammas = 1 - exp(linspace(log(1/512), log(1/32), 8))
  double lo = -6.238324625039508;   // log(1/512)
  double hi = -3.4657359027997265;  // log(1/32)
  double lin = lo + (hi - lo) * ((double)h / 7.0);
  return (float)(1.0 - exp(lin));
}
static __device__ __forceinline__ f32x4 MFMA(short8 a, short8 b, f32x4 c){
  return __builtin_amdgcn_mfma_f32_16x16x32_bf16(a, b, c, 0, 0, 0);
}

// ---------------- fp32 -> bf16 convert (vectorized) ----------------
__global__ void k_cvt(const float* __restrict__ in, unsigned short* __restrict__ out, int n){
  int i = (blockIdx.x*blockDim.x + threadIdx.x)*4;
  int st = gridDim.x*blockDim.x*4;
  for (; i < n; i += st){
    float4 v = *(const float4*)(in + i);
    unsigned short o[4] = { f2b(v.x), f2b(v.y), f2b(v.z), f2b(v.w) };
    *(uint2*)(out + i) = *(const uint2*)o;
  }
}

// ---------------- fp32 [R][C] -> bf16 [C][R] transpose (batched) ----------------
__global__ __launch_bounds__(256) void k_wT(const float* __restrict__ in,
                                            unsigned short* __restrict__ out,
                                            int R, int C){
  __shared__ float tile[32][33];
  in  += (size_t)blockIdx.z * R * C;
  out += (size_t)blockIdx.z * R * C;
  int c0 = blockIdx.x*32, r0 = blockIdx.y*32;
  int tx = threadIdx.x & 31, ty = threadIdx.x >> 5;   // 32 x 8
  #pragma unroll
  for (int i=0;i<4;i++) tile[ty+i*8][tx] = in[(size_t)(r0+ty+i*8)*C + c0+tx];
  __syncthreads();
  #pragma unroll
  for (int i=0;i<4;i++) out[(size_t)(c0+ty+i*8)*R + r0+tx] = f2b(tile[tx][ty+i*8]);
}

// ---------------- qkv projection: per head, bf16 MFMA, no LDS ----------------
__global__ __launch_bounds__(256) void k_qkv(
    const unsigned short* __restrict__ xb,     // [B*S][1024]
    const unsigned short* __restrict__ wqT,    // [H][e=128][d=128]
    const unsigned short* __restrict__ wkT,
    const unsigned short* __restrict__ wvT,
    unsigned short* __restrict__ qb,           // [B][H][S][128]
    unsigned short* __restrict__ kb,
    unsigned short* __restrict__ vb)
{
  int bid = blockIdx.x;            // (b*8+h)*32 + stile
  int stile = bid & 31;
  int bh = bid >> 5;
  int h = bh & 7, b = bh >> 3;
  int t = threadIdx.x, wv = t>>6, l = t&63, lr = l&15, lg = l>>4;
  int row0 = stile*64 + wv*16;
  short8 a[4];
  const unsigned short* xp = xb + (size_t)(b*SS + row0 + lr)*HID + h*HD + lg*8;
  #pragma unroll
  for (int kk=0;kk<4;kk++) a[kk] = *(const short8*)(xp + kk*32);
  size_t obase = ((size_t)bh*SS + row0)*HD;
  const unsigned short* wts[3] = { wqT + (size_t)h*HD*HD, wkT + (size_t)h*HD*HD, wvT + (size_t)h*HD*HD };
  unsigned short* outs[3]      = { qb + obase, kb + obase, vb + obase };
  for (int m=0;m<3;m++){
    const unsigned short* wb = wts[m];
    unsigned short* op = outs[m];
    #pragma unroll
    for (int nt=0;nt<8;nt++){
      f32x4 acc = {0.f,0.f,0.f,0.f};
      #pragma unroll
      for (int kk=0;kk<4;kk++){
        short8 bfr = *(const short8*)(wb + (size_t)(nt*16+lr)*HD + kk*32 + lg*8);
        acc = MFMA(a[kk], bfr, acc);
      }
      #pragma unroll
      for (int r=0;r<4;r++)
        op[(size_t)(lg*4+r)*HD + nt*16 + lr] = f2b(acc[r]);
    }
  }
}

// ---------------- per-chunk KV summary: U[d][e] = sum_m gamma^{127-m} k[m][d] v[m][e] ----------------
__global__ __launch_bounds__(256) void k_chunksum(
    const unsigned short* __restrict__ kb,
    const unsigned short* __restrict__ vb,
    float* __restrict__ U)                    // [B*H*16][128][128]
{
  int bid = blockIdx.x;                       // bh*16 + c
  int c = bid & 15, bh = bid >> 4, h = bh & 7;
  float g = head_gamma(h);
  float l2g = log2f(g);
  __shared__ unsigned short kT[HD][72];
  __shared__ unsigned short vT[HD][72];
  int t = threadIdx.x, wv = t>>6, l = t&63, lr = l&15, lg = l>>4;
  const unsigned short* kc = kb + ((size_t)bh*SS + c*CHK)*HD;
  const unsigned short* vc = vb + ((size_t)bh*SS + c*CHK)*HD;
  f32x4 acc[2][8];
  #pragma unroll
  for (int i=0;i<2;i++)
    #pragma unroll
    for (int j=0;j<8;j++) acc[i][j] = (f32x4){0.f,0.f,0.f,0.f};
  for (int half=0; half<2; half++){
    if (half) __syncthreads();
    #pragma unroll
    for (int it=0; it<4; it++){
      int cid = t + it*256;
      int m = cid >> 4;
      int dc = (cid & 15)*8;
      int mg = half*64 + m;
      short8 kv = *(const short8*)(kc + (size_t)mg*HD + dc);
      short8 vv = *(const short8*)(vc + (size_t)mg*HD + dc);
      float ks = exp2f((float)(CHK-1-mg)*l2g);
      #pragma unroll
      for (int e=0;e<8;e++){
        kT[dc+e][m] = f2b(b2f((unsigned short)kv[e]) * ks);
        vT[dc+e][m] = (unsigned short)vv[e];
      }
    }
    __syncthreads();
    #pragma unroll
    for (int ks=0; ks<2; ks++){
      short8 bfr[8];
      #pragma unroll
      for (int nt=0;nt<8;nt++) bfr[nt] = *(const short8*)&vT[nt*16+lr][ks*32+lg*8];
      #pragma unroll
      for (int mt=0;mt<2;mt++){
        short8 afr = *(const short8*)&kT[wv*32+mt*16+lr][ks*32+lg*8];
        #pragma unroll
        for (int nt=0;nt<8;nt++)
          acc[mt][nt] = MFMA(afr, bfr[nt], acc[mt][nt]);
      }
    }
  }
  float* Up = U + (size_t)bid*HD*HD;
  #pragma unroll
  for (int mt=0;mt<2;mt++)
    #pragma unroll
    for (int nt=0;nt<8;nt++)
      #pragma unroll
      for (int r=0;r<4;r++)
        Up[(size_t)(wv*32+mt*16+lg*4+r)*HD + nt*16+lr] = acc[mt][nt][r];
}

// ---------------- cross-chunk state combine: ST[j][e][d] = sum_{c<j} gamma^{(j-1-c)*128} U[c][d][e] ----------------
__global__ __launch_bounds__(256) void k_state(
    const float* __restrict__ U,
    unsigned short* __restrict__ ST)
{
  int bid = blockIdx.x;                      // bh*16 + j
  int j = bid & 15, bh = bid >> 4, h = bh & 7;
  float g = head_gamma(h);
  float l2g = log2f(g);
  unsigned short* outp = ST + (size_t)bid*HD*HD;
  int t = threadIdx.x;
  float w[15];
  for (int c=0;c<15;c++) w[c] = exp2f((float)((14-c)*CHK)*l2g); // w[c] for (j-1-c) when j==15; reindex below
  for (int i=0;i<64;i++){
    int idx = i*256 + t;
    int d = idx >> 7, e = idx & 127;
    float s = 0.f;
    const float* Ub = U + (size_t)(bh*16)*HD*HD + idx;
    for (int c=0;c<j;c++){
      float wc = exp2f((float)((j-1-c)*CHK)*l2g);
      s += wc * Ub[(size_t)c*HD*HD];
    }
    outp[(size_t)e*HD + d] = f2b(s);
  }
}

// ---------------- retention core per chunk + GroupNorm ----------------
__global__ __launch_bounds__(256) void k_ret(
    const unsigned short* __restrict__ qb,
    const unsigned short* __restrict__ kb,
    const unsigned short* __restrict__ vb,
    const unsigned short* __restrict__ ST,   // [B*H*16][e][d]
    const float* __restrict__ gnw,
    const float* __restrict__ gnb,
    float* __restrict__ ret)                 // [B*S][1024]
{
  int bid = blockIdx.x;                      // bh*16 + j
  int j = bid & 15, bh = bid >> 4, h = bh & 7, b = bh >> 3;
  int p = j*CHK;
  float g = head_gamma(h);
  float l2g = log2f(g);
  __shared__ unsigned short sc[CHK][136];
  __shared__ unsigned short vT[HD][72];
  __shared__ float gpow[CHK];
  int t = threadIdx.x, wv = t>>6, l = t&63, lr = l&15, lg = l>>4;
  if (t < CHK) gpow[t] = exp2f((float)t * l2g);
  const unsigned short* qc = qb + ((size_t)bh*SS + p)*HD;
  const unsigned short* kc = kb + ((size_t)bh*SS + p)*HD;
  const unsigned short* vc = vb + ((size_t)bh*SS + p)*HD;
  const unsigned short* Sp = ST + (size_t)bid*HD*HD;
  __syncthreads();

  auto stageV = [&](int half){
    #pragma unroll
    for (int it=0; it<4; it++){
      int cid = t + it*256;
      int m = cid >> 4;
      int dc = (cid & 15)*8;
      short8 vv = *(const short8*)(vc + (size_t)(half*64 + m)*HD + dc);
      #pragma unroll
      for (int e=0;e<8;e++) vT[dc+e][m] = (unsigned short)vv[e];
    }
  };

  // q fragments for this wave's 32 rows (2 row-tiles x 4 k-steps)
  short8 qf[2][4];
  #pragma unroll
  for (int mt=0;mt<2;mt++)
    #pragma unroll
    for (int kk=0;kk<4;kk++)
      qf[mt][kk] = *(const short8*)(qc + (size_t)(wv*32+mt*16+lr)*HD + kk*32 + lg*8);

  // Phase A: scores = (q k^T) * decay mask -> sc (bf16)
  #pragma unroll
  for (int nt=0;nt<8;nt++){
    f32x4 a0 = {0,0,0,0}, a1 = {0,0,0,0};
    #pragma unroll
    for (int kk=0;kk<4;kk++){
      short8 bfr = *(const short8*)(kc + (size_t)(nt*16+lr)*HD + kk*32 + lg*8);
      a0 = MFMA(qf[0][kk], bfr, a0);
      a1 = MFMA(qf[1][kk], bfr, a1);
    }
    int col = nt*16 + lr;
    #pragma unroll
    for (int r=0;r<4;r++){
      int r0 = wv*32 + lg*4 + r;
      int r1 = r0 + 16;
      float v0 = (col <= r0) ? a0[r]*gpow[r0-col] : 0.f;
      float v1 = (col <= r1) ? a1[r]*gpow[r1-col] : 0.f;
      sc[r0][col] = f2b(v0);
      sc[r1][col] = f2b(v1);
    }
  }
  stageV(0);
  __syncthreads();

  // Phase B: acc = gamma^{row+1} * (q @ S)  then += intra-chunk scores @ v
  f32x4 acc[2][8];
  #pragma unroll
  for (int mt=0;mt<2;mt++)
    #pragma unroll
    for (int nt=0;nt<8;nt++){
      f32x4 a = {0,0,0,0};
      #pragma unroll
      for (int kk=0;kk<4;kk++){
        short8 bfr = *(const short8*)(Sp + (size_t)(nt*16+lr)*HD + kk*32 + lg*8);
        a = MFMA(qf[mt][kk], bfr, a);
      }
      acc[mt][nt] = a;
    }
  #pragma unroll
  for (int mt=0;mt<2;mt++)
    #pragma unroll
    for (int r=0;r<4;r++){
      int rr = wv*32 + mt*16 + lg*4 + r;
      float sf = gpow[rr]*g;
      #pragma unroll
      for (int nt=0;nt<8;nt++) acc[mt][nt][r] *= sf;
    }

  for (int half=0; half<2; half++){
    if (half){ __syncthreads(); stageV(1); __syncthreads(); }
    #pragma unroll
    for (int ks=0; ks<2; ks++){
      short8 bfr[8];
      #pragma unroll
      for (int nt=0;nt<8;nt++) bfr[nt] = *(const short8*)&vT[nt*16+lr][ks*32+lg*8];
      #pragma unroll
      for (int mt=0;mt<2;mt++){
        short8 afr = *(const short8*)&sc[wv*32+mt*16+lr][half*64 + ks*32 + lg*8];
        #pragma unroll
        for (int nt=0;nt<8;nt++)
          acc[mt][nt] = MFMA(afr, bfr[nt], acc[mt][nt]);
      }
    }
  }

  // Epilogue: GroupNorm over d=128 per row, scale/shift, store fp32
  float* rp = ret + ((size_t)(b*SS + p))*HID + h*HD;
  const float* gw  = gnw + h*HD;
  const float* gbb = gnb + h*HD;
  #pragma unroll
  for (int mt=0;mt<2;mt++){
    #pragma unroll
    for (int r=0;r<4;r++){
      float s = 0.f, ss = 0.f;
      #pragma unroll
      for (int nt=0;nt<8;nt++){ float x = acc[mt][nt][r]; s += x; ss += x*x; }
      #pragma unroll
      for (int off=1; off<16; off<<=1){
        s  += __shfl_xor(s,  off, 64);
        ss += __shfl_xor(ss, off, 64);
      }
      float mu  = s*(1.f/128.f);
      float var = ss*(1.f/128.f) - mu*mu;
      float rs  = rsqrtf(var + 1e-5f);
      int rr = wv*32 + mt*16 + lg*4 + r;
      float* orow = rp + (size_t)rr*HID;
      #pragma unroll
      for (int nt=0;nt<8;nt++){
        int col = nt*16 + lr;
        orow[col] = (acc[mt][nt][r]-mu)*rs*gw[col] + gbb[col];
      }
    }
  }
}

// ---------------- 128x128-tile bf16 GEMM (B^T input), epilogue variants ----------------
// EPI==1: Cb = bf16( swish(C) + radd )   EPI==2: Cf = C (fp32)
template<int EPI>
__global__ __launch_bounds__(256) void k_gemm(
    const unsigned short* __restrict__ A,    // [M][K]
    const unsigned short* __restrict__ BT,   // [N][K]
    const float* __restrict__ radd,
    unsigned short* __restrict__ Cb,
    float* __restrict__ Cf,
    int M, int N, int K)
{
  __shared__ unsigned short la[128][72];
  __shared__ unsigned short lb[128][72];
  int nb = N >> 7;
  int m0 = (blockIdx.x / nb) << 7;
  int n0 = (blockIdx.x % nb) << 7;
  int t = threadIdx.x, wv=t>>6, l=t&63, lr=l&15, lg=l>>4;
  int wr = (wv>>1)<<6, wc = (wv&1)<<6;
  f32x4 acc[4][4];
  #pragma unroll
  for (int i=0;i<4;i++)
    #pragma unroll
    for (int jx=0;jx<4;jx++) acc[i][jx] = (f32x4){0,0,0,0};
  for (int k0=0; k0<K; k0+=64){
    if (k0) __syncthreads();
    #pragma unroll
    for (int it=0; it<4; it++){
      int cid = t + it*256;
      int row = cid>>3, kc=(cid&7)*8;
      *(short8*)&la[row][kc] = *(const short8*)(A  + (size_t)(m0+row)*K + k0+kc);
      *(short8*)&lb[row][kc] = *(const short8*)(BT + (size_t)(n0+row)*K + k0+kc);
    }
    __syncthreads();
    #pragma unroll
    for (int ks=0; ks<2; ks++){
      short8 af[4], bf[4];
      #pragma unroll
      for (int i=0;i<4;i++){
        af[i] = *(const short8*)&la[wr+i*16+lr][ks*32+lg*8];
        bf[i] = *(const short8*)&lb[wc+i*16+lr][ks*32+lg*8];
      }
      #pragma unroll
      for (int i=0;i<4;i++)
        #pragma unroll
        for (int jx=0;jx<4;jx++)
          acc[i][jx] = MFMA(af[i], bf[jx], acc[i][jx]);
    }
  }
  #pragma unroll
  for (int i=0;i<4;i++){
    #pragma unroll
    for (int jx=0;jx<4;jx++){
      #pragma unroll
      for (int r=0;r<4;r++){
        int row = m0 + wr + i*16 + lg*4 + r;
        int col = n0 + wc + jx*16 + lr;
        float v = acc[i][jx][r];
        if (EPI == 1){
          float sw = v / (1.f + __expf(-v));
          Cb[(size_t)row*N + col] = f2b(sw + radd[(size_t)row*N + col]);
        } else {
          Cf[(size_t)row*N + col] = v;
        }
      }
    }
  }
}

extern "C" void kernel_launch(void* const* d_in, const int* in_sizes, int n_in,
                              void* d_out, int out_size, void* d_ws, size_t ws_size,
                              hipStream_t stream)
{
  (void)in_sizes; (void)n_in; (void)out_size; (void)ws_size;
  const float* x   = (const float*)d_in[0];
  const float* Wq  = (const float*)d_in[1];
  const float* Wk  = (const float*)d_in[2];
  const float* Wv  = (const float*)d_in[3];
  const float* W1  = (const float*)d_in[4];
  const float* W2  = (const float*)d_in[5];
  const float* gnw = (const float*)d_in[6];
  const float* gnb = (const float*)d_in[7];
  float* out = (float*)d_out;

  char* wsp = (char*)d_ws;
  size_t off = 0;
  auto alloc = [&](size_t bytes)->void*{
    off = (off + 255) & ~(size_t)255;
    void* p = wsp + off; off += bytes; return p;
  };
  const size_t NTOK = (size_t)BB*SS;  // 4096
  unsigned short* xb  = (unsigned short*)alloc(NTOK*HID*2);
  unsigned short* w1T = (unsigned short*)alloc((size_t)HID*HID*2);
  unsigned short* w2T = (unsigned short*)alloc((size_t)HID*HID*2);
  unsigned short* wqT = (unsigned short*)alloc((size_t)NH*HD*HD*2);
  unsigned short* wkT = (unsigned short*)alloc((size_t)NH*HD*HD*2);
  unsigned short* wvT = (unsigned short*)alloc((size_t)NH*HD*HD*2);
  unsigned short* qb  = (unsigned short*)alloc(NTOK*HID*2);
  unsigned short* kb  = (unsigned short*)alloc(NTOK*HID*2);
  unsigned short* vb  = (unsigned short*)alloc(NTOK*HID*2);
  float*          U   = (float*)alloc((size_t)BB*NH*NCH*HD*HD*4);
  unsigned short* ST  = (unsigned short*)alloc((size_t)BB*NH*NCH*HD*HD*2);
  float*          rtb = (float*)alloc(NTOK*HID*4);
  unsigned short* opb = (unsigned short*)alloc(NTOK*HID*2);

  k_cvt<<<dim3(1024), dim3(256), 0, stream>>>(x, xb, (int)(NTOK*HID));
  k_wT<<<dim3(32,32,1), dim3(256), 0, stream>>>(W1, w1T, HID, HID);
  k_wT<<<dim3(32,32,1), dim3(256), 0, stream>>>(W2, w2T, HID, HID);
  k_wT<<<dim3(4,4,NH), dim3(256), 0, stream>>>(Wq, wqT, HD, HD);
  k_wT<<<dim3(4,4,NH), dim3(256), 0, stream>>>(Wk, wkT, HD, HD);
  k_wT<<<dim3(4,4,NH), dim3(256), 0, stream>>>(Wv, wvT, HD, HD);

  k_qkv<<<dim3(BB*NH*32), dim3(256), 0, stream>>>(xb, wqT, wkT, wvT, qb, kb, vb);
  k_chunksum<<<dim3(BB*NH*NCH), dim3(256), 0, stream>>>(kb, vb, U);
  k_state<<<dim3(BB*NH*NCH), dim3(256), 0, stream>>>(U, ST);
  k_ret<<<dim3(BB*NH*NCH), dim3(256), 0, stream>>>(qb, kb, vb, ST, gnw, gnb, rtb);

  k_gemm<1><<<dim3(256), dim3(256), 0, stream>>>(xb,  w1T, rtb, opb, nullptr, (int)NTOK, HID, HID);
  k_gemm<2><<<dim3(256), dim3(256), 0, stream>>>(opb, w2T, nullptr, nullptr, out, (int)NTOK, HID, HID);
}

// Round 2
// 135.888 us; speedup vs baseline: 2.6374x; 2.6374x over previous
//
#include <hip/hip_runtime.h>
#include <hip/hip_bf16.h>

#define HID 1024
#define NH 8
#define HD 128
#define BB 2
#define SS 2048
#define CHK 128
#define NCH 16   // SS/CHK

typedef __attribute__((ext_vector_type(8))) short short8;
typedef __attribute__((ext_vector_type(4))) float f32x4;

static __device__ __forceinline__ float b2f(unsigned short u){
  unsigned int x = ((unsigned int)u) << 16; float f;
  __builtin_memcpy(&f, &x, 4); return f;
}
static __device__ __forceinline__ unsigned short f2b(float f){
  unsigned int x; __builtin_memcpy(&x, &f, 4);
  x += 0x7fffu + ((x >> 16) & 1u);
  return (unsigned short)(x >> 16);
}
static __device__ __forceinline__ float head_gamma(int h){
  // gammas = 1 - exp(linspace(log(1/512), log(1/32), 8))
  double lo = -6.238324625039508;   // log(1/512)
  double hi = -3.4657359027997265;  // log(1/32)
  double lin = lo + (hi - lo) * ((double)h / 7.0);
  return (float)(1.0 - exp(lin));
}
static __device__ __forceinline__ f32x4 MFMA(short8 a, short8 b, f32x4 c){
  return __builtin_amdgcn_mfma_f32_16x16x32_bf16(a, b, c, 0, 0, 0);
}

// ---------------- fp32 -> bf16 convert (vectorized) ----------------
__global__ void k_cvt(const float* __restrict__ in, unsigned short* __restrict__ out, int n){
  int i = (blockIdx.x*blockDim.x + threadIdx.x)*4;
  int st = gridDim.x*blockDim.x*4;
  for (; i < n; i += st){
    float4 v = *(const float4*)(in + i);
    unsigned short o[4] = { f2b(v.x), f2b(v.y), f2b(v.z), f2b(v.w) };
    *(uint2*)(out + i) = *(const uint2*)o;
  }
}

// ---------------- fp32 [R][C] -> bf16 [C][R] transpose (batched) ----------------
__global__ __launch_bounds__(256) void k_wT(const float* __restrict__ in,
                                            unsigned short* __restrict__ out,
                                            int R, int C){
  __shared__ float tile[32][33];
  in  += (size_t)blockIdx.z * R * C;
  out += (size_t)blockIdx.z * R * C;
  int c0 = blockIdx.x*32, r0 = blockIdx.y*32;
  int tx = threadIdx.x & 31, ty = threadIdx.x >> 5;   // 32 x 8
  #pragma unroll
  for (int i=0;i<4;i++) tile[ty+i*8][tx] = in[(size_t)(r0+ty+i*8)*C + c0+tx];
  __syncthreads();
  #pragma unroll
  for (int i=0;i<4;i++) out[(size_t)(c0+ty+i*8)*R + r0+tx] = f2b(tile[tx][ty+i*8]);
}

// ---------------- qkv projection: per head, bf16 MFMA, no LDS ----------------
__global__ __launch_bounds__(256) void k_qkv(
    const unsigned short* __restrict__ xb,     // [B*S][1024]
    const unsigned short* __restrict__ wqT,    // [H][e=128][d=128]
    const unsigned short* __restrict__ wkT,
    const unsigned short* __restrict__ wvT,
    unsigned short* __restrict__ qb,           // [B][H][S][128]
    unsigned short* __restrict__ kb,
    unsigned short* __restrict__ vb)
{
  int bid = blockIdx.x;            // (b*8+h)*32 + stile
  int stile = bid & 31;
  int bh = bid >> 5;
  int h = bh & 7, b = bh >> 3;
  int t = threadIdx.x, wv = t>>6, l = t&63, lr = l&15, lg = l>>4;
  int row0 = stile*64 + wv*16;
  short8 a[4];
  const unsigned short* xp = xb + (size_t)(b*SS + row0 + lr)*HID + h*HD + lg*8;
  #pragma unroll
  for (int kk=0;kk<4;kk++) a[kk] = *(const short8*)(xp + kk*32);
  size_t obase = ((size_t)bh*SS + row0)*HD;
  const unsigned short* wts[3] = { wqT + (size_t)h*HD*HD, wkT + (size_t)h*HD*HD, wvT + (size_t)h*HD*HD };
  unsigned short* outs[3]      = { qb + obase, kb + obase, vb + obase };
  for (int m=0;m<3;m++){
    const unsigned short* wb = wts[m];
    unsigned short* op = outs[m];
    #pragma unroll
    for (int nt=0;nt<8;nt++){
      f32x4 acc = {0.f,0.f,0.f,0.f};
      #pragma unroll
      for (int kk=0;kk<4;kk++){
        short8 bfr = *(const short8*)(wb + (size_t)(nt*16+lr)*HD + kk*32 + lg*8);
        acc = MFMA(a[kk], bfr, acc);
      }
      #pragma unroll
      for (int r=0;r<4;r++)
        op[(size_t)(lg*4+r)*HD + nt*16 + lr] = f2b(acc[r]);
    }
  }
}

// ---------------- per-chunk KV summary (TRANSPOSED OUTPUT):
//   U[e][d] = sum_m gamma^{127-m} v[m][e] k[m][d]  ----------------
__global__ __launch_bounds__(256) void k_chunksum(
    const unsigned short* __restrict__ kb,
    const unsigned short* __restrict__ vb,
    float* __restrict__ U)                    // [B*H*16][e=128][d=128]
{
  int bid = blockIdx.x;                       // bh*16 + c
  int c = bid & 15, bh = bid >> 4, h = bh & 7;
  float g = head_gamma(h);
  float l2g = log2f(g);
  __shared__ unsigned short kT[HD][72];
  __shared__ unsigned short vT[HD][72];
  int t = threadIdx.x, wv = t>>6, l = t&63, lr = l&15, lg = l>>4;
  const unsigned short* kc = kb + ((size_t)bh*SS + c*CHK)*HD;
  const unsigned short* vc = vb + ((size_t)bh*SS + c*CHK)*HD;
  f32x4 acc[2][8];
  #pragma unroll
  for (int i=0;i<2;i++)
    #pragma unroll
    for (int j=0;j<8;j++) acc[i][j] = (f32x4){0.f,0.f,0.f,0.f};
  for (int half=0; half<2; half++){
    if (half) __syncthreads();
    #pragma unroll
    for (int it=0; it<4; it++){
      int cid = t + it*256;
      int m = cid >> 4;
      int dc = (cid & 15)*8;
      int mg = half*64 + m;
      short8 kv = *(const short8*)(kc + (size_t)mg*HD + dc);
      short8 vv = *(const short8*)(vc + (size_t)mg*HD + dc);
      float ks = exp2f((float)(CHK-1-mg)*l2g);
      #pragma unroll
      for (int e=0;e<8;e++){
        kT[dc+e][m] = f2b(b2f((unsigned short)kv[e]) * ks);
        vT[dc+e][m] = (unsigned short)vv[e];
      }
    }
    __syncthreads();
    #pragma unroll
    for (int ks=0; ks<2; ks++){
      short8 bfr[8];
      #pragma unroll
      for (int nt=0;nt<8;nt++) bfr[nt] = *(const short8*)&kT[nt*16+lr][ks*32+lg*8];
      #pragma unroll
      for (int mt=0;mt<2;mt++){
        short8 afr = *(const short8*)&vT[wv*32+mt*16+lr][ks*32+lg*8];
        #pragma unroll
        for (int nt=0;nt<8;nt++)
          acc[mt][nt] = MFMA(afr, bfr[nt], acc[mt][nt]);
      }
    }
  }
  // output row = e (from vT), col = d (from kT) -> U[e][d], coalesced
  float* Up = U + (size_t)bid*HD*HD;
  #pragma unroll
  for (int mt=0;mt<2;mt++)
    #pragma unroll
    for (int nt=0;nt<8;nt++)
      #pragma unroll
      for (int r=0;r<4;r++)
        Up[(size_t)(wv*32+mt*16+lg*4+r)*HD + nt*16+lr] = acc[mt][nt][r];
}

// ---------------- cross-chunk state scan: S_0 = 0; S_j = g^128 * S_{j-1} + U[j-1]
//   fully coalesced, 16-step serial scan per element ----------------
__global__ __launch_bounds__(256) void k_state(
    const float* __restrict__ U,              // [B*H][16][128*128] ([e][d])
    unsigned short* __restrict__ ST)          // [B*H][16][128*128] ([e][d])
{
  int bid = blockIdx.x;                       // bh*64 + eb
  int eb = bid & 63, bh = bid >> 6, h = bh & 7;
  float g = head_gamma(h);
  float d128 = exp2f(128.f * log2f(g));       // gamma^128
  int idx = eb*256 + threadIdx.x;
  const float* Ub = U + (size_t)bh*NCH*HD*HD + idx;
  unsigned short* Sb = ST + (size_t)bh*NCH*HD*HD + idx;
  float s = 0.f;
  #pragma unroll
  for (int c=0;c<NCH;c++){
    Sb[(size_t)c*HD*HD] = f2b(s);
    s = s*d128 + Ub[(size_t)c*HD*HD];
  }
}

// ---------------- retention core per chunk + GroupNorm ----------------
__global__ __launch_bounds__(256) void k_ret(
    const unsigned short* __restrict__ qb,
    const unsigned short* __restrict__ kb,
    const unsigned short* __restrict__ vb,
    const unsigned short* __restrict__ ST,   // [B*H*16][e][d]
    const float* __restrict__ gnw,
    const float* __restrict__ gnb,
    float* __restrict__ ret)                 // [B*S][1024]
{
  int bid = blockIdx.x;                      // bh*16 + j
  int j = bid & 15, bh = bid >> 4, h = bh & 7, b = bh >> 3;
  int p = j*CHK;
  float g = head_gamma(h);
  float l2g = log2f(g);
  __shared__ unsigned short sc[CHK][136];
  __shared__ unsigned short vT[HD][72];
  __shared__ float gpow[CHK];
  int t = threadIdx.x, wv = t>>6, l = t&63, lr = l&15, lg = l>>4;
  if (t < CHK) gpow[t] = exp2f((float)t * l2g);
  const unsigned short* qc = qb + ((size_t)bh*SS + p)*HD;
  const unsigned short* kc = kb + ((size_t)bh*SS + p)*HD;
  const unsigned short* vc = vb + ((size_t)bh*SS + p)*HD;
  const unsigned short* Sp = ST + (size_t)bid*HD*HD;
  __syncthreads();

  auto stageV = [&](int half){
    #pragma unroll
    for (int it=0; it<4; it++){
      int cid = t + it*256;
      int m = cid >> 4;
      int dc = (cid & 15)*8;
      short8 vv = *(const short8*)(vc + (size_t)(half*64 + m)*HD + dc);
      #pragma unroll
      for (int e=0;e<8;e++) vT[dc+e][m] = (unsigned short)vv[e];
    }
  };

  // q fragments for this wave's 32 rows (2 row-tiles x 4 k-steps)
  short8 qf[2][4];
  #pragma unroll
  for (int mt=0;mt<2;mt++)
    #pragma unroll
    for (int kk=0;kk<4;kk++)
      qf[mt][kk] = *(const short8*)(qc + (size_t)(wv*32+mt*16+lr)*HD + kk*32 + lg*8);

  // Phase A: scores = (q k^T) * decay mask -> sc (bf16)
  #pragma unroll
  for (int nt=0;nt<8;nt++){
    f32x4 a0 = {0,0,0,0}, a1 = {0,0,0,0};
    #pragma unroll
    for (int kk=0;kk<4;kk++){
      short8 bfr = *(const short8*)(kc + (size_t)(nt*16+lr)*HD + kk*32 + lg*8);
      a0 = MFMA(qf[0][kk], bfr, a0);
      a1 = MFMA(qf[1][kk], bfr, a1);
    }
    int col = nt*16 + lr;
    #pragma unroll
    for (int r=0;r<4;r++){
      int r0 = wv*32 + lg*4 + r;
      int r1 = r0 + 16;
      float v0 = (col <= r0) ? a0[r]*gpow[r0-col] : 0.f;
      float v1 = (col <= r1) ? a1[r]*gpow[r1-col] : 0.f;
      sc[r0][col] = f2b(v0);
      sc[r1][col] = f2b(v1);
    }
  }
  stageV(0);
  __syncthreads();

  // Phase B: acc = gamma^{row+1} * (q @ S)  then += intra-chunk scores @ v
  f32x4 acc[2][8];
  #pragma unroll
  for (int mt=0;mt<2;mt++)
    #pragma unroll
    for (int nt=0;nt<8;nt++){
      f32x4 a = {0,0,0,0};
      #pragma unroll
      for (int kk=0;kk<4;kk++){
        short8 bfr = *(const short8*)(Sp + (size_t)(nt*16+lr)*HD + kk*32 + lg*8);
        a = MFMA(qf[mt][kk], bfr, a);
      }
      acc[mt][nt] = a;
    }
  #pragma unroll
  for (int mt=0;mt<2;mt++)
    #pragma unroll
    for (int r=0;r<4;r++){
      int rr = wv*32 + mt*16 + lg*4 + r;
      float sf = gpow[rr]*g;
      #pragma unroll
      for (int nt=0;nt<8;nt++) acc[mt][nt][r] *= sf;
    }

  for (int half=0; half<2; half++){
    if (half){ __syncthreads(); stageV(1); __syncthreads(); }
    #pragma unroll
    for (int ks=0; ks<2; ks++){
      short8 bfr[8];
      #pragma unroll
      for (int nt=0;nt<8;nt++) bfr[nt] = *(const short8*)&vT[nt*16+lr][ks*32+lg*8];
      #pragma unroll
      for (int mt=0;mt<2;mt++){
        short8 afr = *(const short8*)&sc[wv*32+mt*16+lr][half*64 + ks*32 + lg*8];
        #pragma unroll
        for (int nt=0;nt<8;nt++)
          acc[mt][nt] = MFMA(afr, bfr[nt], acc[mt][nt]);
      }
    }
  }

  // Epilogue: GroupNorm over d=128 per row, scale/shift, store fp32
  float* rp = ret + ((size_t)(b*SS + p))*HID + h*HD;
  const float* gw  = gnw + h*HD;
  const float* gbb = gnb + h*HD;
  #pragma unroll
  for (int mt=0;mt<2;mt++){
    #pragma unroll
    for (int r=0;r<4;r++){
      float s = 0.f, ss = 0.f;
      #pragma unroll
      for (int nt=0;nt<8;nt++){ float x = acc[mt][nt][r]; s += x; ss += x*x; }
      #pragma unroll
      for (int off=1; off<16; off<<=1){
        s  += __shfl_xor(s,  off, 64);
        ss += __shfl_xor(ss, off, 64);
      }
      float mu  = s*(1.f/128.f);
      float var = ss*(1.f/128.f) - mu*mu;
      float rs  = rsqrtf(var + 1e-5f);
      int rr = wv*32 + mt*16 + lg*4 + r;
      float* orow = rp + (size_t)rr*HID;
      #pragma unroll
      for (int nt=0;nt<8;nt++){
        int col = nt*16 + lr;
        orow[col] = (acc[mt][nt][r]-mu)*rs*gw[col] + gbb[col];
      }
    }
  }
}

// ---------------- 128x128-tile bf16 GEMM (B^T input), epilogue variants ----------------
// EPI==1: Cb = bf16( swish(C) + radd )   EPI==2: Cf = C (fp32)
template<int EPI>
__global__ __launch_bounds__(256) void k_gemm(
    const unsigned short* __restrict__ A,    // [M][K]
    const unsigned short* __restrict__ BT,   // [N][K]
    const float* __restrict__ radd,
    unsigned short* __restrict__ Cb,
    float* __restrict__ Cf,
    int M, int N, int K)
{
  __shared__ unsigned short la[128][72];
  __shared__ unsigned short lb[128][72];
  int nb = N >> 7;
  int m0 = (blockIdx.x / nb) << 7;
  int n0 = (blockIdx.x % nb) << 7;
  int t = threadIdx.x, wv=t>>6, l=t&63, lr=l&15, lg=l>>4;
  int wr = (wv>>1)<<6, wc = (wv&1)<<6;
  f32x4 acc[4][4];
  #pragma unroll
  for (int i=0;i<4;i++)
    #pragma unroll
    for (int jx=0;jx<4;jx++) acc[i][jx] = (f32x4){0,0,0,0};
  for (int k0=0; k0<K; k0+=64){
    if (k0) __syncthreads();
    #pragma unroll
    for (int it=0; it<4; it++){
      int cid = t + it*256;
      int row = cid>>3, kc=(cid&7)*8;
      *(short8*)&la[row][kc] = *(const short8*)(A  + (size_t)(m0+row)*K + k0+kc);
      *(short8*)&lb[row][kc] = *(const short8*)(BT + (size_t)(n0+row)*K + k0+kc);
    }
    __syncthreads();
    #pragma unroll
    for (int ks=0; ks<2; ks++){
      short8 af[4], bf[4];
      #pragma unroll
      for (int i=0;i<4;i++){
        af[i] = *(const short8*)&la[wr+i*16+lr][ks*32+lg*8];
        bf[i] = *(const short8*)&lb[wc+i*16+lr][ks*32+lg*8];
      }
      #pragma unroll
      for (int i=0;i<4;i++)
        #pragma unroll
        for (int jx=0;jx<4;jx++)
          acc[i][jx] = MFMA(af[i], bf[jx], acc[i][jx]);
    }
  }
  #pragma unroll
  for (int i=0;i<4;i++){
    #pragma unroll
    for (int jx=0;jx<4;jx++){
      #pragma unroll
      for (int r=0;r<4;r++){
        int row = m0 + wr + i*16 + lg*4 + r;
        int col = n0 + wc + jx*16 + lr;
        float v = acc[i][jx][r];
        if (EPI == 1){
          float sw = v / (1.f + __expf(-v));
          Cb[(size_t)row*N + col] = f2b(sw + radd[(size_t)row*N + col]);
        } else {
          Cf[(size_t)row*N + col] = v;
        }
      }
    }
  }
}

extern "C" void kernel_launch(void* const* d_in, const int* in_sizes, int n_in,
                              void* d_out, int out_size, void* d_ws, size_t ws_size,
                              hipStream_t stream)
{
  (void)in_sizes; (void)n_in; (void)out_size; (void)ws_size;
  const float* x   = (const float*)d_in[0];
  const float* Wq  = (const float*)d_in[1];
  const float* Wk  = (const float*)d_in[2];
  const float* Wv  = (const float*)d_in[3];
  const float* W1  = (const float*)d_in[4];
  const float* W2  = (const float*)d_in[5];
  const float* gnw = (const float*)d_in[6];
  const float* gnb = (const float*)d_in[7];
  float* out = (float*)d_out;

  char* wsp = (char*)d_ws;
  size_t off = 0;
  auto alloc = [&](size_t bytes)->void*{
    off = (off + 255) & ~(size_t)255;
    void* p = wsp + off; off += bytes; return p;
  };
  const size_t NTOK = (size_t)BB*SS;  // 4096
  unsigned short* xb  = (unsigned short*)alloc(NTOK*HID*2);
  unsigned short* w1T = (unsigned short*)alloc((size_t)HID*HID*2);
  unsigned short* w2T = (unsigned short*)alloc((size_t)HID*HID*2);
  unsigned short* wqT = (unsigned short*)alloc((size_t)NH*HD*HD*2);
  unsigned short* wkT = (unsigned short*)alloc((size_t)NH*HD*HD*2);
  unsigned short* wvT = (unsigned short*)alloc((size_t)NH*HD*HD*2);
  unsigned short* qb  = (unsigned short*)alloc(NTOK*HID*2);
  unsigned short* kb  = (unsigned short*)alloc(NTOK*HID*2);
  unsigned short* vb  = (unsigned short*)alloc(NTOK*HID*2);
  float*          U   = (float*)alloc((size_t)BB*NH*NCH*HD*HD*4);
  unsigned short* ST  = (unsigned short*)alloc((size_t)BB*NH*NCH*HD*HD*2);
  float*          rtb = (float*)alloc(NTOK*HID*4);
  unsigned short* opb = (unsigned short*)alloc(NTOK*HID*2);

  k_cvt<<<dim3(1024), dim3(256), 0, stream>>>(x, xb, (int)(NTOK*HID));
  k_wT<<<dim3(32,32,1), dim3(256), 0, stream>>>(W1, w1T, HID, HID);
  k_wT<<<dim3(32,32,1), dim3(256), 0, stream>>>(W2, w2T, HID, HID);
  k_wT<<<dim3(4,4,NH), dim3(256), 0, stream>>>(Wq, wqT, HD, HD);
  k_wT<<<dim3(4,4,NH), dim3(256), 0, stream>>>(Wk, wkT, HD, HD);
  k_wT<<<dim3(4,4,NH), dim3(256), 0, stream>>>(Wv, wvT, HD, HD);

  k_qkv<<<dim3(BB*NH*32), dim3(256), 0, stream>>>(xb, wqT, wkT, wvT, qb, kb, vb);
  k_chunksum<<<dim3(BB*NH*NCH), dim3(256), 0, stream>>>(kb, vb, U);
  k_state<<<dim3(BB*NH*64), dim3(256), 0, stream>>>(U, ST);
  k_ret<<<dim3(BB*NH*NCH), dim3(256), 0, stream>>>(qb, kb, vb, ST, gnw, gnb, rtb);

  k_gemm<1><<<dim3(256), dim3(256), 0, stream>>>(xb,  w1T, rtb, opb, nullptr, (int)NTOK, HID, HID);
  k_gemm<2><<<dim3(256), dim3(256), 0, stream>>>(opb, w2T, nullptr, nullptr, out, (int)NTOK, HID, HID);
}